// Round 4
// baseline (157.357 us; speedup 1.0000x reference)
//
#include <hip/hip_runtime.h>
#include <math.h>

#define D 128
#define EPS 1e-6f
#define SKR_LD 136            // shorts per row, row-major sigma [32][D]
#define SKT_LD 40             // shorts per row, transposed sigma [D][32]
#define DV_LD  40             // shorts per row, dvT [D][32]
#define SKR_SZ (32 * SKR_LD)  // 4352 shorts
#define SKT_SZ (128 * SKT_LD) // 5120 shorts

typedef __attribute__((ext_vector_type(8))) short short8;
typedef __attribute__((ext_vector_type(4))) float f32x4;
typedef unsigned short ushort_t;
typedef unsigned long long u64;

__device__ __forceinline__ float elu1(float x) {
    float e = __expf(fminf(x, 0.f));
    return x > 0.f ? x + 1.f : e;
}
__device__ __forceinline__ unsigned short bf16rne(float f) {
    unsigned u = __builtin_bit_cast(unsigned, f);
    u += 0x7FFFu + ((u >> 16) & 1u);
    return (unsigned short)(u >> 16);
}
__device__ __forceinline__ u64 pack4(float a, float b, float c, float d) {
    return (u64)bf16rne(a) | ((u64)bf16rne(b) << 16) |
           ((u64)bf16rne(c) << 32) | ((u64)bf16rne(d) << 48);
}

// ---------------------------------------------------------------------------
// Update: per (bh, chunk): pM = sigma_k^T @ (V - (sigma_k@M)/(sigma_k@z+eps)),
// pz = sum_s sigma_k.  512 threads = 8 waves; wave w owns e-tile w.
// Round-2-proven layouts: skR row-major [32][D] (LD 136), skT transposed
// [D][32] (LD 40).  Normalizer via replicated-z MFMA; delta_v B-frags via
// intra-wave dvT LDS roundtrip (no barrier needed: DS pipe in-order per wave).
// One barrier per 32-row batch.
// ---------------------------------------------------------------------------
__global__ __launch_bounds__(512, 4)
void k_update(const float* __restrict__ key, const float* __restrict__ value,
              const float* __restrict__ M, const float* __restrict__ z,
              float* __restrict__ pM, float* __restrict__ pz, int S)
{
    __shared__ alignas(16) ushort_t skR[2 * SKR_SZ];
    __shared__ alignas(16) ushort_t skT[2 * SKT_SZ];
    __shared__ alignas(16) ushort_t dvT[128 * DV_LD];

    const int t  = threadIdx.x;
    const int bh = blockIdx.x, ch = blockIdx.y, NCH = gridDim.y;
    const int SC = S / NCH, NB = SC / 32, s0g = ch * SC;

    const int w = t >> 6, g = (t >> 4) & 3, m = t & 15;  // compute roles
    const int c2 = t & 63;                               // stage: rows 4w..4w+3, cols 2c2,2c2+1

    const float* Kb = key   + (size_t)bh * S * D;
    const float* Vb = value + (size_t)bh * S * D;
    const float* Mb = M + (size_t)bh * D * D;
    const float* zb = z + (size_t)bh * D;

    // B-frags in registers: M columns (this wave's e-tile) and replicated z
    short8 Bf[4], zf[4];
    #pragma unroll
    for (int ks = 0; ks < 4; ++ks) {
        short8 f, zfr;
        #pragma unroll
        for (int j = 0; j < 8; ++j) {
            f[j]   = (short)bf16rne(Mb[(size_t)(32 * ks + 8 * g + j) * D + 16 * w + m]);
            zfr[j] = (short)bf16rne(zb[32 * ks + 8 * g + j]);
        }
        Bf[ks] = f; zf[ks] = zfr;
    }

    f32x4 acc[8];
    #pragma unroll
    for (int dt = 0; dt < 8; ++dt) acc[dt] = 0.f;
    float zacc0 = 0.f, zacc1 = 0.f;

    // stage: elu(K rows) -> skR (row-major) + skT (transposed); z partials
    auto STAGE = [&](const float2* kr, int buf) {
        float sv0[4], sv1[4];
        #pragma unroll
        for (int i = 0; i < 4; ++i) { sv0[i] = elu1(kr[i].x); sv1[i] = elu1(kr[i].y); }
        #pragma unroll
        for (int i = 0; i < 4; ++i)
            *(unsigned*)&skR[buf * SKR_SZ + (4 * w + i) * SKR_LD + 2 * c2] =
                (unsigned)bf16rne(sv0[i]) | ((unsigned)bf16rne(sv1[i]) << 16);
        *(u64*)&skT[buf * SKT_SZ + (2 * c2) * SKT_LD + 4 * w] =
            pack4(sv0[0], sv0[1], sv0[2], sv0[3]);
        *(u64*)&skT[buf * SKT_SZ + (2 * c2 + 1) * SKT_LD + 4 * w] =
            pack4(sv1[0], sv1[1], sv1[2], sv1[3]);
        zacc0 += sv0[0] + sv0[1] + sv0[2] + sv0[3];
        zacc1 += sv1[0] + sv1[1] + sv1[2] + sv1[3];
    };

    { // prologue: stage batch 0
        float2 kr[4];
        #pragma unroll
        for (int i = 0; i < 4; ++i)
            kr[i] = *(const float2*)&Kb[(size_t)(s0g + 4 * w + i) * D + 2 * c2];
        STAGE(kr, 0);
    }
    __syncthreads();

    for (int b = 0; b < NB; ++b) {
        const int cur = b & 1;
        const int sbat = s0g + 32 * b;

        // prefetch K(b+1)
        float2 kr[4];
        if (b + 1 < NB) {
            #pragma unroll
            for (int i = 0; i < 4; ++i)
                kr[i] = *(const float2*)&Kb[(size_t)(sbat + 32 + 4 * w + i) * D + 2 * c2];
        }

        // V loads (this wave's e-tile)
        float vv[2][4];
        #pragma unroll
        for (int st = 0; st < 2; ++st)
            #pragma unroll
            for (int r = 0; r < 4; ++r)
                vv[st][r] = Vb[(size_t)(sbat + 16 * st + 4 * g + r) * D + 16 * w + m];

        // MFMA1: mem_pred and normalizer (replicated-z trick)
        f32x4 mp[2], mz[2];
        #pragma unroll
        for (int st = 0; st < 2; ++st) { mp[st] = 0.f; mz[st] = 0.f; }
        #pragma unroll
        for (int st = 0; st < 2; ++st)
            #pragma unroll
            for (int ks = 0; ks < 4; ++ks) {
                short8 a = *(short8*)&skR[cur * SKR_SZ + (16 * st + m) * SKR_LD + 32 * ks + 8 * g];
                mp[st] = __builtin_amdgcn_mfma_f32_16x16x32_bf16(a, Bf[ks], mp[st], 0, 0, 0);
                mz[st] = __builtin_amdgcn_mfma_f32_16x16x32_bf16(a, zf[ks], mz[st], 0, 0, 0);
            }

        // delta_v -> dvT[e][s] (intra-wave: rows 16w+m belong to wave w only)
        #pragma unroll
        for (int st = 0; st < 2; ++st) {
            float dv[4];
            #pragma unroll
            for (int r = 0; r < 4; ++r)
                dv[r] = vv[st][r] - mp[st][r] / (mz[st][r] + EPS);
            *(u64*)&dvT[(16 * w + m) * DV_LD + 16 * st + 4 * g] =
                pack4(dv[0], dv[1], dv[2], dv[3]);
        }
        asm volatile("" ::: "memory");  // fence: dvT write -> read (TBAA guard)

        // B2-frag: dv[s=8g..8g+7][e=16w+m]
        short8 bfr = *(short8*)&dvT[(16 * w + m) * DV_LD + 8 * g];

        // MFMA2: acc += sigma^T @ delta_v
        #pragma unroll
        for (int dt = 0; dt < 8; ++dt) {
            short8 a2 = *(short8*)&skT[cur * SKT_SZ + (16 * dt + m) * SKT_LD + 8 * g];
            acc[dt] = __builtin_amdgcn_mfma_f32_16x16x32_bf16(a2, bfr, acc[dt], 0, 0, 0);
        }

        if (b + 1 < NB) STAGE(kr, cur ^ 1);
        __syncthreads();
    }

    // write pM partial
    float* pMb = pM + ((size_t)bh * NCH + ch) * (D * D);
    #pragma unroll
    for (int dt = 0; dt < 8; ++dt)
        #pragma unroll
        for (int r = 0; r < 4; ++r)
            pMb[(size_t)(16 * dt + 4 * g + r) * D + 16 * w + m] = acc[dt][r];

    // z partial: reduce the 8 wave-row-groups via LDS aliased on skR
    float* zsc = (float*)skR;   // [8][128]
    zsc[w * 128 + 2 * c2]     = zacc0;
    zsc[w * 128 + 2 * c2 + 1] = zacc1;
    __syncthreads();
    if (t < 128) {
        float a = 0.f;
        #pragma unroll
        for (int r = 0; r < 8; ++r) a += zsc[r * 128 + t];
        pz[((size_t)bh * NCH + ch) * D + t] = a;
    }
}

// ---------------------------------------------------------------------------
// Reduce: M_new = M + sum_ch pM ; z_new = z + sum_ch pz
// ---------------------------------------------------------------------------
__global__ void k_reduce(const float* __restrict__ M, const float* __restrict__ z,
                         const float* __restrict__ pM, const float* __restrict__ pz,
                         float* __restrict__ Mnew, float* __restrict__ znew, int NCH)
{
    const int bh = blockIdx.x, sl = blockIdx.y, t = threadIdx.x;
    const size_t baseM = (size_t)bh * D * D;
    for (int i = sl * 2048 + t; i < (sl + 1) * 2048; i += 256) {
        float a = M[baseM + i];
        for (int c = 0; c < NCH; ++c) a += pM[((size_t)bh * NCH + c) * (D * D) + i];
        Mnew[baseM + i] = a;
    }
    if (sl == 0 && t < D) {
        float a = z[(size_t)bh * D + t];
        for (int c = 0; c < NCH; ++c) a += pz[((size_t)bh * NCH + c) * D + t];
        znew[(size_t)bh * D + t] = a;
    }
}

// ---------------------------------------------------------------------------
// Retrieve: out = (sigma_q @ M_new) / (sigma_q @ z_new + eps)
// (unchanged from round 2 — proven correct, near memory floor)
// ---------------------------------------------------------------------------
__global__ __launch_bounds__(256, 2)
void k_retrieve(const float* __restrict__ query, const float* __restrict__ Mnew,
                const float* __restrict__ znew, float* __restrict__ out, int S)
{
    __shared__ alignas(16) ushort_t sqR[2][32 * SKR_LD];
    __shared__ float normsh[2][32];

    const int t  = threadIdx.x;
    const int bh = blockIdx.x, ch = blockIdx.y, NCH = gridDim.y;
    const int SC = S / NCH;
    const int NB = SC / 32;
    const int s0g = ch * SC;

    const int w = t >> 6, g = (t >> 4) & 3, m = t & 15;
    const int sb = t >> 5, db = t & 31;

    const float* Qb = query + (size_t)bh * S * D;
    const float* Mb = Mnew + (size_t)bh * D * D;
    const float* zb = znew + (size_t)bh * D;
    float*       Ob = out + (size_t)bh * S * D;

    float zr[4];
    #pragma unroll
    for (int j = 0; j < 4; ++j) zr[j] = zb[4 * db + j];

    short8 Bf[4][2];
    #pragma unroll
    for (int ks = 0; ks < 4; ++ks)
        #pragma unroll
        for (int p = 0; p < 2; ++p) {
            short8 f;
            #pragma unroll
            for (int j = 0; j < 8; ++j)
                f[j] = (short)bf16rne(Mb[(size_t)(32 * ks + 8 * g + j) * D + 16 * (2 * w + p) + m]);
            Bf[ks][p] = f;
        }

    auto STAGE_PROC = [&](const float4* qreg, int bu) {
        float sv[4][4];
        #pragma unroll
        for (int js = 0; js < 4; ++js) {
            sv[js][0] = elu1(qreg[js].x); sv[js][1] = elu1(qreg[js].y);
            sv[js][2] = elu1(qreg[js].z); sv[js][3] = elu1(qreg[js].w);
        }
        #pragma unroll
        for (int js = 0; js < 4; ++js)
            *(u64*)&sqR[bu][(4 * sb + js) * SKR_LD + 4 * db] =
                pack4(sv[js][0], sv[js][1], sv[js][2], sv[js][3]);
        float np[4];
        #pragma unroll
        for (int js = 0; js < 4; ++js)
            np[js] = sv[js][0] * zr[0] + sv[js][1] * zr[1] +
                     sv[js][2] * zr[2] + sv[js][3] * zr[3];
        #pragma unroll
        for (int mask = 16; mask >= 1; mask >>= 1) {
            np[0] += __shfl_xor(np[0], mask, 64);
            np[1] += __shfl_xor(np[1], mask, 64);
            np[2] += __shfl_xor(np[2], mask, 64);
            np[3] += __shfl_xor(np[3], mask, 64);
        }
        if (db < 4) {
            float v = db == 0 ? np[0] : db == 1 ? np[1] : db == 2 ? np[2] : np[3];
            normsh[bu][4 * sb + db] = v + EPS;
        }
    };

    {
        float4 qreg[4];
        #pragma unroll
        for (int js = 0; js < 4; ++js)
            qreg[js] = *(const float4*)&Qb[(size_t)(s0g + 4 * sb + js) * D + 4 * db];
        STAGE_PROC(qreg, 0);
    }
    __syncthreads();

    for (int b = 0; b < NB; ++b) {
        const int bu = b & 1;
        float4 qreg[4];
        if (b + 1 < NB) {
            #pragma unroll
            for (int js = 0; js < 4; ++js)
                qreg[js] = *(const float4*)&Qb[(size_t)(s0g + 32 * (b + 1) + 4 * sb + js) * D + 4 * db];
        }

        f32x4 mp[2][2];
        #pragma unroll
        for (int st = 0; st < 2; ++st)
            #pragma unroll
            for (int p = 0; p < 2; ++p) mp[st][p] = 0.f;
        #pragma unroll
        for (int st = 0; st < 2; ++st)
            #pragma unroll
            for (int ks = 0; ks < 4; ++ks) {
                short8 a = *(short8*)&sqR[bu][(16 * st + m) * SKR_LD + 32 * ks + 8 * g];
                #pragma unroll
                for (int p = 0; p < 2; ++p)
                    mp[st][p] = __builtin_amdgcn_mfma_f32_16x16x32_bf16(a, Bf[ks][p], mp[st][p], 0, 0, 0);
            }

        #pragma unroll
        for (int st = 0; st < 2; ++st)
            #pragma unroll
            for (int r = 0; r < 4; ++r) {
                float rn = 1.f / normsh[bu][16 * st + 4 * g + r];
                #pragma unroll
                for (int p = 0; p < 2; ++p)
                    Ob[(size_t)(s0g + 32 * b + 16 * st + 4 * g + r) * D + 16 * (2 * w + p) + m] =
                        mp[st][p][r] * rn;
            }

        if (b + 1 < NB) STAGE_PROC(qreg, (b + 1) & 1);
        __syncthreads();
    }
}

// ---------------------------------------------------------------------------
extern "C" void kernel_launch(void* const* d_in, const int* in_sizes, int n_in,
                              void* d_out, int out_size, void* d_ws, size_t ws_size,
                              hipStream_t stream)
{
    const float* q = (const float*)d_in[0];
    const float* k = (const float*)d_in[1];
    const float* v = (const float*)d_in[2];
    const float* M = (const float*)d_in[3];
    const float* z = (const float*)d_in[4];

    const int BH = in_sizes[3] / (D * D);
    const int S  = in_sizes[0] / (BH * D);

    float* out  = (float*)d_out;
    float* Mnew = out + (size_t)BH * S * D;
    float* znew = Mnew + (size_t)BH * D * D;

    int NCH = 8;
    const size_t per_set = (size_t)BH * (D * D + D) * sizeof(float);
    while (NCH > 1 && (size_t)NCH * per_set > ws_size) NCH >>= 1;

    float* pM;
    float* pz;
    if ((size_t)NCH * per_set <= ws_size) {
        pM = (float*)d_ws;
        pz = pM + (size_t)NCH * BH * D * D;
    } else {
        NCH = 1;
        pM = Mnew;
        pz = znew;
    }

    dim3 gridA(BH, NCH);
    k_update<<<gridA, 512, 0, stream>>>(k, v, M, z, pM, pz, S);
    dim3 gridB(BH, 8);
    k_reduce<<<gridB, 256, 0, stream>>>(M, z, pM, pz, Mnew, znew, NCH);
    dim3 gridC(BH, 8);
    k_retrieve<<<gridC, 256, 0, stream>>>(q, Mnew, znew, out, S);
}